// Round 12
// baseline (489.962 us; speedup 1.0000x reference)
//
#include <hip/hip_runtime.h>

#define N_NODES_C 50000
#define N_EDGES_C 600000
#define NODE_DIM_C 64
#define EDGE_DIM_C 16
#define HID 128
#define N_GRAPHS_C 256
#define BN_EPS_C 1e-5f
#define SCAN_NBLK ((N_NODES_C + 255) / 256)  // 196

typedef short bf16x8 __attribute__((ext_vector_type(8)));
typedef float f32x4 __attribute__((ext_vector_type(4)));
typedef float f32x2 __attribute__((ext_vector_type(2)));

__device__ __forceinline__ unsigned short f2bf(float f) {
  union { float f; unsigned u; } v; v.f = f;
  unsigned r = (v.u + 0x7fffu + ((v.u >> 16) & 1u)) >> 16;
  return (unsigned short)r;
}

__device__ __forceinline__ float2 bfp2f(unsigned u) {
  union { unsigned u; float f; } lo, hi;
  lo.u = u << 16;
  hi.u = u & 0xffff0000u;
  return make_float2(lo.f, hi.f);
}

__device__ __forceinline__ float bf2f(unsigned short s) {
  union { unsigned u; float f; } v;
  v.u = ((unsigned)s) << 16;
  return v.f;
}

// 2 fp8 (e4m3, HW) packed in low 16 bits -> 2 floats
__device__ __forceinline__ float2 fp8p2f(unsigned short u) {
  f32x2 r = __builtin_amdgcn_cvt_pk_f32_fp8((int)(unsigned)u, false);
  return make_float2(r.x, r.y);
}

// ---------- x -> bf16 conversion; also zero-inits cnt_cur and g ----------
__global__ __launch_bounds__(256)
void k_x2bf(const float* __restrict__ x, unsigned short* __restrict__ xb,
            int* __restrict__ cnt, float* __restrict__ g) {
  int tid = blockIdx.x * 256 + threadIdx.x;
  size_t i = (size_t)tid * 4;
  if (i < (size_t)N_NODES_C * NODE_DIM_C) {
    float4 v = *(const float4*)&x[i];
    uint2 o;
    o.x = (unsigned)f2bf(v.x) | ((unsigned)f2bf(v.y) << 16);
    o.y = (unsigned)f2bf(v.z) | ((unsigned)f2bf(v.w) << 16);
    *(uint2*)&xb[i] = o;
  }
  if (tid < N_NODES_C) cnt[tid] = 0;
  if (tid < N_GRAPHS_C * HID) g[tid] = 0.f;
}

// ------- weight prep: 6 MLP mats -> wT[m][n*128+k]; node_w -> nwT[n*64+k] ---
__global__ __launch_bounds__(256)
void k_prep_w(const float* __restrict__ w1, const float* __restrict__ w2,
              const float* __restrict__ nodew, unsigned short* __restrict__ wT) {
  int m = blockIdx.x;  // 0..6
  if (m < 6) {
    const float* src = (m < 3) ? (w1 + (size_t)m * HID * HID)
                               : (w2 + (size_t)(m - 3) * HID * HID);
    unsigned short* dst = wT + (size_t)m * HID * HID;
    for (int i = threadIdx.x; i < HID * HID; i += 256) {
      int n = i >> 7, k = i & 127;
      dst[n * HID + k] = f2bf(src[k * HID + n]);
    }
  } else {
    unsigned short* dst = wT + (size_t)6 * HID * HID;  // [128][64]
    for (int i = threadIdx.x; i < HID * NODE_DIM_C; i += 256) {
      int n = i >> 6, k = i & 63;
      dst[n * NODE_DIM_C + k] = f2bf(nodew[k * HID + n]);
    }
  }
}

// ------- node encoder via MFMA: h = bf16(x_bf @ node_w + node_b), K=64 ------
__global__ __launch_bounds__(256)
void k_node_mfma(const unsigned short* __restrict__ xb,
                 const unsigned short* __restrict__ nwT,
                 const float* __restrict__ bias, unsigned short* __restrict__ h) {
  const int LD = NODE_DIM_C + 8;  // 72
  __shared__ unsigned short a_lds[128 * LD];  // 18 KB
  __shared__ unsigned short w_lds[128 * LD];  // 18 KB
  int t = threadIdx.x;
  int row0 = blockIdx.x * 128;
  {
    int r = t >> 3, c = t & 7;
#pragma unroll
    for (int it = 0; it < 4; ++it) {
      int row = it * 32 + r;
      int grow = row0 + row;
      uint4 va = (grow < N_NODES_C)
                     ? ((const uint4*)(xb + (size_t)grow * NODE_DIM_C))[c]
                     : make_uint4(0, 0, 0, 0);
      *(uint4*)&a_lds[row * LD + c * 8] = va;
      uint4 vw = ((const uint4*)(nwT + (size_t)row * NODE_DIM_C))[c];
      *(uint4*)&w_lds[row * LD + c * 8] = vw;
    }
  }
  __syncthreads();

  int lane = t & 63;
  int w = t >> 6;
  int l15 = lane & 15;
  int q = lane >> 4;

  f32x4 acc[2][8];
#pragma unroll
  for (int rt = 0; rt < 2; ++rt)
#pragma unroll
    for (int nt = 0; nt < 8; ++nt) acc[rt][nt] = (f32x4)0.f;

#pragma unroll
  for (int kk = 0; kk < 2; ++kk) {
    int k0 = kk * 32;
    bf16x8 af[2];
#pragma unroll
    for (int rt = 0; rt < 2; ++rt) {
      int arow = w * 32 + rt * 16 + l15;
      af[rt] = *(const bf16x8*)&a_lds[arow * LD + k0 + q * 8];
    }
#pragma unroll
    for (int nt = 0; nt < 8; ++nt) {
      bf16x8 bf = *(const bf16x8*)&w_lds[(nt * 16 + l15) * LD + k0 + q * 8];
#pragma unroll
      for (int rt = 0; rt < 2; ++rt)
        acc[rt][nt] = __builtin_amdgcn_mfma_f32_16x16x32_bf16(af[rt], bf, acc[rt][nt], 0, 0, 0);
    }
  }

#pragma unroll
  for (int nt = 0; nt < 8; ++nt) {
    int gcol = nt * 16 + l15;
    float bv = bias[gcol];
#pragma unroll
    for (int rt = 0; rt < 2; ++rt) {
#pragma unroll
      for (int i = 0; i < 4; ++i) {
        int grow = row0 + w * 32 + rt * 16 + q * 4 + i;
        if (grow < N_NODES_C) h[(size_t)grow * HID + gcol] = f2bf(acc[rt][nt][i] + bv);
      }
    }
  }
}

// ---------------- CSR build (counting sort by dst) ----------------
__global__ __launch_bounds__(256)
void k_histogram(const int* __restrict__ dst, int* __restrict__ counts) {
  int e = blockIdx.x * 256 + threadIdx.x;
  if (e < N_EDGES_C) atomicAdd(&counts[dst[e]], 1);
}

__global__ __launch_bounds__(256)
void k_blocksum(const int* __restrict__ cnt, int* __restrict__ partial) {
  __shared__ int ls[4];
  int t = threadIdx.x;
  int i = blockIdx.x * 256 + t;
  int v = (i < N_NODES_C) ? cnt[i] : 0;
#pragma unroll
  for (int o = 32; o > 0; o >>= 1) v += __shfl_down(v, o, 64);
  if ((t & 63) == 0) ls[t >> 6] = v;
  __syncthreads();
  if (t == 0) partial[blockIdx.x] = ls[0] + ls[1] + ls[2] + ls[3];
}

__global__ __launch_bounds__(256)
void k_scanpartials(const int* __restrict__ partial, int* __restrict__ partial_off) {
  __shared__ int s[256];
  int t = threadIdx.x;
  int v = (t < SCAN_NBLK) ? partial[t] : 0;
  s[t] = v;
  __syncthreads();
  for (int d = 1; d < 256; d <<= 1) {
    int x = (t >= d) ? s[t - d] : 0;
    __syncthreads();
    s[t] += x;
    __syncthreads();
  }
  if (t < SCAN_NBLK) partial_off[t] = s[t] - v;
}

__global__ __launch_bounds__(256)
void k_apply(int* __restrict__ cnt_cursor, const int* __restrict__ partial_off,
             int* __restrict__ row_ptr) {
  __shared__ int s[256];
  int t = threadIdx.x;
  int i = blockIdx.x * 256 + t;
  int v = (i < N_NODES_C) ? cnt_cursor[i] : 0;
  s[t] = v;
  __syncthreads();
  for (int d = 1; d < 256; d <<= 1) {
    int x = (t >= d) ? s[t - d] : 0;
    __syncthreads();
    s[t] += x;
    __syncthreads();
  }
  int excl = s[t] - v + partial_off[blockIdx.x];
  if (i < N_NODES_C) {
    row_ptr[i] = excl;
    cnt_cursor[i] = excl;
  }
  if (i == 0) row_ptr[N_NODES_C] = N_EDGES_C;
}

// bucket: single 8B scattered store per edge
__global__ __launch_bounds__(256)
void k_bucket(const int* __restrict__ dst, const int* __restrict__ srcArr,
              int* __restrict__ cursor, int2* __restrict__ edata) {
  int e = blockIdx.x * 256 + threadIdx.x;
  if (e < N_EDGES_C) {
    int d = dst[e];
    int s = srcArr[e];
    int p = atomicAdd(&cursor[d], 1);
    edata[p] = make_int2(e, s);
  }
}

// ---- edge encoder via MFMA (operand-swapped): D = W^T · A_edges^T so each
// lane's D-fragment holds 4 consecutive wcols of ONE edge -> direct fp8 pack
// + 4B global store. No LDS out-tile, no second barrier, no bf16 rounding.
// Also emits src_perm coalesced.
#define EE_LDW 40   // A/W row stride (shorts); K padded 16->32 + 8 pad
__global__ __launch_bounds__(256)
void k_edge_encode(const int2* __restrict__ edata, const float* __restrict__ eattr,
                   const float* __restrict__ ew, const float* __restrict__ ebias,
                   unsigned char* __restrict__ ea8, int* __restrict__ src_perm) {
  __shared__ unsigned short a_lds[128 * EE_LDW];  // edges [128][40], 10.2 KB
  __shared__ unsigned short w_lds[128 * EE_LDW];  // wcols [128][40], 10.2 KB
  int t = threadIdx.x;
  int EB = blockIdx.x * 128;

  // stage W^T: one thread per wcol n; w_lds[n][k] = W[k][n], zero k=16..31
  if (t < 128) {
    unsigned short tmp[16];
#pragma unroll
    for (int k = 0; k < 16; ++k) tmp[k] = f2bf(ew[k * HID + t]);
    uint4* wr = (uint4*)&w_lds[t * EE_LDW];
    wr[0] = *(uint4*)&tmp[0];
    wr[1] = *(uint4*)&tmp[8];
    wr[2] = make_uint4(0, 0, 0, 0);
    wr[3] = make_uint4(0, 0, 0, 0);
  }
  // stage A: 2 threads per edge; a_lds[edge][k], zero k=16..31
  {
    int edge = t >> 1, half = t & 1;
    int gi = EB + edge;
    float4 v0 = make_float4(0, 0, 0, 0), v1 = v0;
    if (gi < N_EDGES_C) {
      int2 ed = edata[gi];
      if (half == 0) src_perm[gi] = ed.y;
      const float4* p = (const float4*)(eattr + (size_t)ed.x * EDGE_DIM_C + half * 8);
      v0 = p[0];
      v1 = p[1];
    }
    unsigned short tmp[8] = {f2bf(v0.x), f2bf(v0.y), f2bf(v0.z), f2bf(v0.w),
                             f2bf(v1.x), f2bf(v1.y), f2bf(v1.z), f2bf(v1.w)};
    *(uint4*)&a_lds[edge * EE_LDW + half * 8] = *(uint4*)tmp;
    *(uint4*)&a_lds[edge * EE_LDW + 16 + half * 8] = make_uint4(0, 0, 0, 0);
  }
  __syncthreads();

  int lane = t & 63;
  int w = t >> 6;
  int l15 = lane & 15;
  int q = lane >> 4;

  // A-operand: wave w covers wcols [w*32, w*32+32) (rt=0..1), lane m=l15
  bf16x8 wf[2];
#pragma unroll
  for (int rt = 0; rt < 2; ++rt)
    wf[rt] = *(const bf16x8*)&w_lds[(w * 32 + rt * 16 + l15) * EE_LDW + q * 8];

  f32x4 acc[2][8];
#pragma unroll
  for (int nt = 0; nt < 8; ++nt) {
    // B-operand: edge tile nt, lane n=l15
    bf16x8 ef = *(const bf16x8*)&a_lds[(nt * 16 + l15) * EE_LDW + q * 8];
#pragma unroll
    for (int rt = 0; rt < 2; ++rt)
      acc[rt][nt] = __builtin_amdgcn_mfma_f32_16x16x32_bf16(
          wf[rt], ef, (f32x4)0.f, 0, 0, 0);
  }

  // bias: wcol = w*32 + rt*16 + q*4 + i (independent of nt)
  float bv[2][4];
#pragma unroll
  for (int rt = 0; rt < 2; ++rt)
#pragma unroll
    for (int i = 0; i < 4; ++i) bv[rt][i] = ebias[w * 32 + rt * 16 + q * 4 + i];

#pragma unroll
  for (int nt = 0; nt < 8; ++nt) {
    int edge = EB + nt * 16 + l15;
    if (edge < N_EDGES_C) {
#pragma unroll
      for (int rt = 0; rt < 2; ++rt) {
        int r = __builtin_amdgcn_cvt_pk_fp8_f32(acc[rt][nt][0] + bv[rt][0],
                                                acc[rt][nt][1] + bv[rt][1], 0, false);
        r = __builtin_amdgcn_cvt_pk_fp8_f32(acc[rt][nt][2] + bv[rt][2],
                                            acc[rt][nt][3] + bv[rt][3], r, true);
        *(unsigned*)&ea8[(size_t)edge * 128 + w * 32 + rt * 16 + q * 4] = (unsigned)r;
      }
    }
  }
}

// -------- aggregate: z[n] = h[n] + sum_{e: dst=n} relu(h[src_e] + ea_e) -----
__global__ __launch_bounds__(256)
void k_aggregate(const unsigned* __restrict__ h32, const unsigned char* __restrict__ ea8,
                 const int* __restrict__ src_p, const int* __restrict__ row_ptr,
                 unsigned short* __restrict__ z, float* __restrict__ gsum,
                 float* __restrict__ gsumsq) {
  int t = threadIdx.x;
  if (blockIdx.x == 0 && t < HID) { gsum[t] = 0.f; gsumsq[t] = 0.f; }
  int lane = t & 63;
  int wave = t >> 6;
  int node = blockIdx.x * 4 + wave;
  if (node >= N_NODES_C) return;
  float2 base = bfp2f(h32[(size_t)node * 64 + lane]);
  float acc0 = base.x, acc1 = base.y;
  int beg = row_ptr[node], end = row_ptr[node + 1];
  const unsigned char* eap = ea8 + lane * 2;
  int j = beg;
  for (; j + 8 <= end; j += 8) {
    int s0 = src_p[j],     s1 = src_p[j + 1], s2 = src_p[j + 2], s3 = src_p[j + 3];
    int s4 = src_p[j + 4], s5 = src_p[j + 5], s6 = src_p[j + 6], s7 = src_p[j + 7];
    unsigned g0 = h32[(size_t)s0 * 64 + lane];
    unsigned g1 = h32[(size_t)s1 * 64 + lane];
    unsigned g2 = h32[(size_t)s2 * 64 + lane];
    unsigned g3 = h32[(size_t)s3 * 64 + lane];
    unsigned g4 = h32[(size_t)s4 * 64 + lane];
    unsigned g5 = h32[(size_t)s5 * 64 + lane];
    unsigned g6 = h32[(size_t)s6 * 64 + lane];
    unsigned g7 = h32[(size_t)s7 * 64 + lane];
    unsigned short u0 = *(const unsigned short*)(eap + (size_t)j * 128);
    unsigned short u1 = *(const unsigned short*)(eap + (size_t)(j + 1) * 128);
    unsigned short u2 = *(const unsigned short*)(eap + (size_t)(j + 2) * 128);
    unsigned short u3 = *(const unsigned short*)(eap + (size_t)(j + 3) * 128);
    unsigned short u4 = *(const unsigned short*)(eap + (size_t)(j + 4) * 128);
    unsigned short u5 = *(const unsigned short*)(eap + (size_t)(j + 5) * 128);
    unsigned short u6 = *(const unsigned short*)(eap + (size_t)(j + 6) * 128);
    unsigned short u7 = *(const unsigned short*)(eap + (size_t)(j + 7) * 128);
    float2 a0 = bfp2f(g0), a1 = bfp2f(g1), a2 = bfp2f(g2), a3 = bfp2f(g3);
    float2 a4 = bfp2f(g4), a5 = bfp2f(g5), a6 = bfp2f(g6), a7 = bfp2f(g7);
    float2 e0 = fp8p2f(u0), e1 = fp8p2f(u1), e2 = fp8p2f(u2), e3 = fp8p2f(u3);
    float2 e4 = fp8p2f(u4), e5 = fp8p2f(u5), e6 = fp8p2f(u6), e7 = fp8p2f(u7);
    acc0 += fmaxf(a0.x + e0.x, 0.f) + fmaxf(a1.x + e1.x, 0.f) +
            fmaxf(a2.x + e2.x, 0.f) + fmaxf(a3.x + e3.x, 0.f) +
            fmaxf(a4.x + e4.x, 0.f) + fmaxf(a5.x + e5.x, 0.f) +
            fmaxf(a6.x + e6.x, 0.f) + fmaxf(a7.x + e7.x, 0.f);
    acc1 += fmaxf(a0.y + e0.y, 0.f) + fmaxf(a1.y + e1.y, 0.f) +
            fmaxf(a2.y + e2.y, 0.f) + fmaxf(a3.y + e3.y, 0.f) +
            fmaxf(a4.y + e4.y, 0.f) + fmaxf(a5.y + e5.y, 0.f) +
            fmaxf(a6.y + e6.y, 0.f) + fmaxf(a7.y + e7.y, 0.f);
  }
  for (; j + 4 <= end; j += 4) {
    int s0 = src_p[j], s1 = src_p[j + 1], s2 = src_p[j + 2], s3 = src_p[j + 3];
    unsigned g0 = h32[(size_t)s0 * 64 + lane];
    unsigned g1 = h32[(size_t)s1 * 64 + lane];
    unsigned g2 = h32[(size_t)s2 * 64 + lane];
    unsigned g3 = h32[(size_t)s3 * 64 + lane];
    unsigned short u0 = *(const unsigned short*)(eap + (size_t)j * 128);
    unsigned short u1 = *(const unsigned short*)(eap + (size_t)(j + 1) * 128);
    unsigned short u2 = *(const unsigned short*)(eap + (size_t)(j + 2) * 128);
    unsigned short u3 = *(const unsigned short*)(eap + (size_t)(j + 3) * 128);
    float2 a0 = bfp2f(g0), a1 = bfp2f(g1), a2 = bfp2f(g2), a3 = bfp2f(g3);
    float2 e0 = fp8p2f(u0), e1 = fp8p2f(u1), e2 = fp8p2f(u2), e3 = fp8p2f(u3);
    acc0 += fmaxf(a0.x + e0.x, 0.f) + fmaxf(a1.x + e1.x, 0.f) +
            fmaxf(a2.x + e2.x, 0.f) + fmaxf(a3.x + e3.x, 0.f);
    acc1 += fmaxf(a0.y + e0.y, 0.f) + fmaxf(a1.y + e1.y, 0.f) +
            fmaxf(a2.y + e2.y, 0.f) + fmaxf(a3.y + e3.y, 0.f);
  }
  for (; j < end; ++j) {
    int s0 = src_p[j];
    float2 a0 = bfp2f(h32[(size_t)s0 * 64 + lane]);
    float2 e0 = fp8p2f(*(const unsigned short*)(eap + (size_t)j * 128));
    acc0 += fmaxf(a0.x + e0.x, 0.f);
    acc1 += fmaxf(a0.y + e0.y, 0.f);
  }
  unsigned packed = (unsigned)f2bf(acc0) | ((unsigned)f2bf(acc1) << 16);
  *(unsigned*)&z[(size_t)node * HID + lane * 2] = packed;
}

// ---- fused MLP: t2 = (relu(z@w1+b1))@w2+b2, both GEMMs in one kernel ------
__global__ __launch_bounds__(256)
void k_mlp_fused(const unsigned short* __restrict__ in,
                 const unsigned short* __restrict__ w1T,
                 const float* __restrict__ b1,
                 const unsigned short* __restrict__ w2T,
                 const float* __restrict__ b2,
                 unsigned short* __restrict__ outb,
                 float* __restrict__ gsum, float* __restrict__ gsumsq) {
  const int LDA = HID + 8;  // 136
  const int OS = 132;       // t1 tile stride: epilogue write conflict-free
  __shared__ unsigned short a_lds[128 * LDA];  // 34.8 KB (z, then t1 @ stride OS)
  __shared__ unsigned short w_lds[128 * LDA];  // 34.8 KB (w1T, then w2T)
  int t = threadIdx.x;
  int row0 = blockIdx.x * 128;
  {
    int r = t >> 4, chunk = t & 15;
#pragma unroll
    for (int it = 0; it < 8; ++it) {
      int row = it * 16 + r;
      int grow = row0 + row;
      uint4 va = (grow < N_NODES_C)
                     ? ((const uint4*)(in + (size_t)grow * HID))[chunk]
                     : make_uint4(0, 0, 0, 0);
      *(uint4*)&a_lds[row * LDA + chunk * 8] = va;
      uint4 vw = ((const uint4*)(w1T + (size_t)row * HID))[chunk];
      *(uint4*)&w_lds[row * LDA + chunk * 8] = vw;
    }
  }
  __syncthreads();

  int lane = t & 63;
  int w = t >> 6;
  int l15 = lane & 15;
  int q = lane >> 4;

  // ---- pass 1: z @ w1 ----
  f32x4 acc[2][8];
#pragma unroll
  for (int rt = 0; rt < 2; ++rt)
#pragma unroll
    for (int nt = 0; nt < 8; ++nt) acc[rt][nt] = (f32x4)0.f;

#pragma unroll
  for (int kk = 0; kk < 4; ++kk) {
    int k0 = kk * 32;
    bf16x8 af[2];
#pragma unroll
    for (int rt = 0; rt < 2; ++rt) {
      int arow = w * 32 + rt * 16 + l15;
      af[rt] = *(const bf16x8*)&a_lds[arow * LDA + k0 + q * 8];
    }
#pragma unroll
    for (int nt = 0; nt < 8; ++nt) {
      int brow = nt * 16 + l15;
      bf16x8 bf = *(const bf16x8*)&w_lds[brow * LDA + k0 + q * 8];
#pragma unroll
      for (int rt = 0; rt < 2; ++rt)
        acc[rt][nt] = __builtin_amdgcn_mfma_f32_16x16x32_bf16(af[rt], bf, acc[rt][nt], 0, 0, 0);
    }
  }
  __syncthreads();  // all pass-1 LDS reads done; safe to overwrite

  // t1 = bf16(relu(acc + b1)) -> a_lds at stride OS; restage w2T -> w_lds
#pragma unroll
  for (int nt = 0; nt < 8; ++nt) {
    int col = nt * 16 + l15;
    float bv = b1[col];
#pragma unroll
    for (int rt = 0; rt < 2; ++rt) {
#pragma unroll
      for (int i = 0; i < 4; ++i) {
        int row = w * 32 + rt * 16 + q * 4 + i;
        a_lds[row * OS + col] = f2bf(fmaxf(acc[rt][nt][i] + bv, 0.f));
      }
    }
  }
  {
    int r = t >> 4, chunk = t & 15;
#pragma unroll
    for (int it = 0; it < 8; ++it) {
      int row = it * 16 + r;
      uint4 vw = ((const uint4*)(w2T + (size_t)row * HID))[chunk];
      *(uint4*)&w_lds[row * LDA + chunk * 8] = vw;
    }
  }
  __syncthreads();

  // ---- pass 2: t1 @ w2 ----
#pragma unroll
  for (int rt = 0; rt < 2; ++rt)
#pragma unroll
    for (int nt = 0; nt < 8; ++nt) acc[rt][nt] = (f32x4)0.f;

#pragma unroll
  for (int kk = 0; kk < 4; ++kk) {
    int k0 = kk * 32;
    bf16x8 af[2];
#pragma unroll
    for (int rt = 0; rt < 2; ++rt) {
      int arow = w * 32 + rt * 16 + l15;
      af[rt] = *(const bf16x8*)&a_lds[arow * OS + k0 + q * 8];
    }
#pragma unroll
    for (int nt = 0; nt < 8; ++nt) {
      int brow = nt * 16 + l15;
      bf16x8 bf = *(const bf16x8*)&w_lds[brow * LDA + k0 + q * 8];
#pragma unroll
      for (int rt = 0; rt < 2; ++rt)
        acc[rt][nt] = __builtin_amdgcn_mfma_f32_16x16x32_bf16(af[rt], bf, acc[rt][nt], 0, 0, 0);
    }
  }

  float sp[8], qp[8];
#pragma unroll
  for (int nt = 0; nt < 8; ++nt) { sp[nt] = 0.f; qp[nt] = 0.f; }

#pragma unroll
  for (int nt = 0; nt < 8; ++nt) {
    int gcol = nt * 16 + l15;
    float bv = b2[gcol];
#pragma unroll
    for (int rt = 0; rt < 2; ++rt) {
#pragma unroll
      for (int i = 0; i < 4; ++i) {
        int grow = row0 + w * 32 + rt * 16 + q * 4 + i;
        bool ok = (grow < N_NODES_C);
        float v = acc[rt][nt][i] + bv;
        if (ok) outb[(size_t)grow * HID + gcol] = f2bf(v);
        float c = ok ? v : 0.f;
        sp[nt] += c;
        qp[nt] += c * c;
      }
    }
  }

  __syncthreads();  // all pass-2 LDS reads done; reuse a_lds as reduce scratch
  float* sred = (float*)a_lds;        // [128][16]
  float* qred = sred + 128 * 16;
  int slot = w * 4 + q;
#pragma unroll
  for (int nt = 0; nt < 8; ++nt) {
    int gcol = nt * 16 + l15;
    sred[gcol * 16 + slot] = sp[nt];
    qred[gcol * 16 + slot] = qp[nt];
  }
  __syncthreads();
  if (t < 128) {
    float s = 0.f;
#pragma unroll
    for (int i = 0; i < 16; ++i) s += sred[t * 16 + i];
    atomicAdd(&gsum[t], s);
  } else {
    int f = t - 128;
    float s = 0.f;
#pragma unroll
    for (int i = 0; i < 16; ++i) s += qred[f * 16 + i];
    atomicAdd(&gsumsq[f], s);
  }
}

// BN (finalize folded in) + relu: reads t2 bf16, writes h bf16 (layers 0,1)
__global__ __launch_bounds__(256)
void k_bn_relu(const unsigned short* __restrict__ t2, const float* __restrict__ gsum,
               const float* __restrict__ gsumsq, const float* __restrict__ gamma,
               const float* __restrict__ beta, unsigned short* __restrict__ h) {
  __shared__ float sc[HID], sh[HID];
  int t = threadIdx.x;
  if (t < HID) {
    float mean = gsum[t] * (1.f / N_NODES_C);
    float var = gsumsq[t] * (1.f / N_NODES_C) - mean * mean;
    float inv = rsqrtf(var + BN_EPS_C);
    float s = gamma[t] * inv;
    sc[t] = s;
    sh[t] = beta[t] - mean * s;
  }
  __syncthreads();
  size_t idx = ((size_t)blockIdx.x * 256 + t) * 8;
  if (idx < (size_t)N_NODES_C * HID) {
    uint4 v = *(const uint4*)&t2[idx];
    int f = (int)(idx & 127);
    float2 p0 = bfp2f(v.x), p1 = bfp2f(v.y), p2 = bfp2f(v.z), p3 = bfp2f(v.w);
    float r0 = fmaxf(p0.x * sc[f + 0] + sh[f + 0], 0.f);
    float r1 = fmaxf(p0.y * sc[f + 1] + sh[f + 1], 0.f);
    float r2 = fmaxf(p1.x * sc[f + 2] + sh[f + 2], 0.f);
    float r3 = fmaxf(p1.y * sc[f + 3] + sh[f + 3], 0.f);
    float r4 = fmaxf(p2.x * sc[f + 4] + sh[f + 4], 0.f);
    float r5 = fmaxf(p2.y * sc[f + 5] + sh[f + 5], 0.f);
    float r6 = fmaxf(p3.x * sc[f + 6] + sh[f + 6], 0.f);
    float r7 = fmaxf(p3.y * sc[f + 7] + sh[f + 7], 0.f);
    uint4 o;
    o.x = (unsigned)f2bf(r0) | ((unsigned)f2bf(r1) << 16);
    o.y = (unsigned)f2bf(r2) | ((unsigned)f2bf(r3) << 16);
    o.z = (unsigned)f2bf(r4) | ((unsigned)f2bf(r5) << 16);
    o.w = (unsigned)f2bf(r6) | ((unsigned)f2bf(r7) << 16);
    *(uint4*)&h[idx] = o;
  }
}

// BN (finalize folded in) + relu + global_add_pool fused (last layer)
__global__ __launch_bounds__(128)
void k_bn_relu_pool(const unsigned short* __restrict__ t2, const float* __restrict__ gsum,
                    const float* __restrict__ gsumsq, const float* __restrict__ gamma,
                    const float* __restrict__ beta, const int* __restrict__ batch,
                    float* __restrict__ g) {
  int t = threadIdx.x;
  float mean = gsum[t] * (1.f / N_NODES_C);
  float var = gsumsq[t] * (1.f / N_NODES_C) - mean * mean;
  float inv = rsqrtf(var + BN_EPS_C);
  float sc = gamma[t] * inv;
  float sh = beta[t] - mean * sc;
  int n0 = blockIdx.x * 64;
  if (n0 >= N_NODES_C) return;
  int end = min(n0 + 64, N_NODES_C);
  int cur = batch[n0];
  float acc = 0.f;
  for (int n = n0; n < end; ++n) {
    int b = batch[n];
    if (b != cur) {
      atomicAdd(&g[cur * HID + t], acc);
      acc = 0.f;
      cur = b;
    }
    acc += fmaxf(bf2f(t2[(size_t)n * HID + t]) * sc + sh, 0.f);
  }
  atomicAdd(&g[cur * HID + t], acc);
}

// ---------------- head: relu(g@w1+b1)@w2+b2 ----------------
__global__ __launch_bounds__(128)
void k_head(const float* __restrict__ g, const float* __restrict__ w1,
            const float* __restrict__ b1, const float* __restrict__ w2,
            const float* __restrict__ b2, float* __restrict__ out) {
  __shared__ float gs[HID];
  __shared__ float red[HID * 2];
  int gi = blockIdx.x, t = threadIdx.x;
  gs[t] = g[gi * HID + t];
  __syncthreads();
  float acc = b1[t];
#pragma unroll 8
  for (int k = 0; k < HID; ++k) acc += gs[k] * w1[k * HID + t];
  float hid = fmaxf(acc, 0.f);
  red[t * 2] = hid * w2[t * 2];
  red[t * 2 + 1] = hid * w2[t * 2 + 1];
  __syncthreads();
  for (int s = 64; s > 0; s >>= 1) {
    if (t < s) { red[t * 2] += red[(t + s) * 2]; red[t * 2 + 1] += red[(t + s) * 2 + 1]; }
    __syncthreads();
  }
  if (t == 0) {
    out[gi * 2] = red[0] + b2[0];
    out[gi * 2 + 1] = red[1] + b2[1];
  }
}

extern "C" void kernel_launch(void* const* d_in, const int* in_sizes, int n_in,
                              void* d_out, int out_size, void* d_ws, size_t ws_size,
                              hipStream_t stream) {
  const float* x      = (const float*)d_in[0];
  const int*   eidx   = (const int*)d_in[1];
  const float* eattr  = (const float*)d_in[2];
  const int*   batch  = (const int*)d_in[3];
  const float* node_w = (const float*)d_in[4];
  const float* node_b = (const float*)d_in[5];
  const float* edge_w = (const float*)d_in[6];
  const float* edge_b = (const float*)d_in[7];
  const float* mlp_w1 = (const float*)d_in[8];
  const float* mlp_b1 = (const float*)d_in[9];
  const float* mlp_w2 = (const float*)d_in[10];
  const float* mlp_b2 = (const float*)d_in[11];
  const float* bn_g   = (const float*)d_in[12];
  const float* bn_b   = (const float*)d_in[13];
  const float* hw1    = (const float*)d_in[14];
  const float* hb1    = (const float*)d_in[15];
  const float* hw2    = (const float*)d_in[16];
  const float* hb2    = (const float*)d_in[17];
  const int* srcArr = eidx;
  const int* dstArr = eidx + N_EDGES_C;

  char* wsp = (char*)d_ws;
  size_t off = 0;
  auto alloc = [&](size_t bytes) {
    void* p = wsp + off;
    off += (bytes + 255) & ~(size_t)255;
    return p;
  };
  unsigned short* h    = (unsigned short*)alloc((size_t)N_NODES_C * HID * 2);   // 12.8 MB
  unsigned short* zbf  = (unsigned short*)alloc((size_t)N_NODES_C * HID * 2);   // 12.8 MB
  unsigned short* t2bf = (unsigned short*)alloc((size_t)N_NODES_C * HID * 2);   // 12.8 MB
  unsigned char* ea8   = (unsigned char*)alloc((size_t)N_EDGES_C * HID);        // 76.8 MB
  unsigned short* xb   = (unsigned short*)alloc((size_t)N_NODES_C * NODE_DIM_C * 2);  // 6.4 MB
  unsigned short* wT   = (unsigned short*)alloc(((size_t)6 * HID * HID + HID * NODE_DIM_C) * 2);
  int* row_ptr   = (int*)alloc((N_NODES_C + 1) * 4);
  int* cnt_cur   = (int*)alloc(N_NODES_C * 4);
  int2* edata    = (int2*)alloc((size_t)N_EDGES_C * 8);  // 4.8 MB
  int* src_perm  = (int*)alloc((size_t)N_EDGES_C * 4);
  int* partial   = (int*)alloc(256 * 4);
  int* partial_off = (int*)alloc(256 * 4);
  float* gsum    = (float*)alloc(HID * 4);
  float* gsumsq  = (float*)alloc(HID * 4);
  float* g       = (float*)alloc((size_t)N_GRAPHS_C * HID * 4);
  unsigned short* nwT = wT + (size_t)6 * HID * HID;

  k_x2bf<<<(N_NODES_C * NODE_DIM_C / 4 + 255) / 256, 256, 0, stream>>>(x, xb,
                                                                       cnt_cur, g);
  k_prep_w<<<7, 256, 0, stream>>>(mlp_w1, mlp_w2, node_w, wT);
  k_node_mfma<<<(N_NODES_C + 127) / 128, 256, 0, stream>>>(xb, nwT, node_b, h);
  k_histogram<<<(N_EDGES_C + 255) / 256, 256, 0, stream>>>(dstArr, cnt_cur);
  k_blocksum<<<SCAN_NBLK, 256, 0, stream>>>(cnt_cur, partial);
  k_scanpartials<<<1, 256, 0, stream>>>(partial, partial_off);
  k_apply<<<SCAN_NBLK, 256, 0, stream>>>(cnt_cur, partial_off, row_ptr);
  k_bucket<<<(N_EDGES_C + 255) / 256, 256, 0, stream>>>(dstArr, srcArr, cnt_cur,
                                                        edata);
  k_edge_encode<<<(N_EDGES_C + 127) / 128, 256, 0, stream>>>(edata, eattr, edge_w,
                                                             edge_b, ea8, src_perm);

  const int GB = (N_NODES_C + 127) / 128;  // 391
  for (int l = 0; l < 3; ++l) {
    k_aggregate<<<(N_NODES_C + 3) / 4, 256, 0, stream>>>((const unsigned*)h, ea8,
                                                         src_perm, row_ptr, zbf,
                                                         gsum, gsumsq);
    k_mlp_fused<<<GB, 256, 0, stream>>>(
        zbf, wT + (size_t)l * HID * HID, mlp_b1 + l * HID,
        wT + (size_t)(3 + l) * HID * HID, mlp_b2 + l * HID, t2bf, gsum, gsumsq);
    if (l < 2) {
      k_bn_relu<<<(N_NODES_C * HID / 8 + 255) / 256, 256, 0, stream>>>(
          t2bf, gsum, gsumsq, bn_g + l * HID, bn_b + l * HID, h);
    } else {
      k_bn_relu_pool<<<(N_NODES_C + 63) / 64, 128, 0, stream>>>(
          t2bf, gsum, gsumsq, bn_g + l * HID, bn_b + l * HID, batch, g);
    }
  }
  k_head<<<N_GRAPHS_C, 128, 0, stream>>>(g, hw1, hb1, hw2, hb2, (float*)d_out);
}

// Round 13
// 469.236 us; speedup vs baseline: 1.0442x; 1.0442x over previous
//
#include <hip/hip_runtime.h>

#define N_NODES_C 50000
#define N_EDGES_C 600000
#define NODE_DIM_C 64
#define EDGE_DIM_C 16
#define HID 128
#define N_GRAPHS_C 256
#define BN_EPS_C 1e-5f
#define SCAN_NBLK ((N_NODES_C + 255) / 256)  // 196

typedef short bf16x8 __attribute__((ext_vector_type(8)));
typedef float f32x4 __attribute__((ext_vector_type(4)));
typedef float f32x2 __attribute__((ext_vector_type(2)));

__device__ __forceinline__ unsigned short f2bf(float f) {
  union { float f; unsigned u; } v; v.f = f;
  unsigned r = (v.u + 0x7fffu + ((v.u >> 16) & 1u)) >> 16;
  return (unsigned short)r;
}

__device__ __forceinline__ float2 bfp2f(unsigned u) {
  union { unsigned u; float f; } lo, hi;
  lo.u = u << 16;
  hi.u = u & 0xffff0000u;
  return make_float2(lo.f, hi.f);
}

__device__ __forceinline__ float bf2f(unsigned short s) {
  union { unsigned u; float f; } v;
  v.u = ((unsigned)s) << 16;
  return v.f;
}

// 2 fp8 (e4m3, HW) packed in low 16 bits -> 2 floats
__device__ __forceinline__ float2 fp8p2f(unsigned short u) {
  f32x2 r = __builtin_amdgcn_cvt_pk_f32_fp8((int)(unsigned)u, false);
  return make_float2(r.x, r.y);
}

// ---- x -> bf16 conversion; zero-inits cnt_cur, g, gsum, gsumsq ----
__global__ __launch_bounds__(256)
void k_x2bf(const float* __restrict__ x, unsigned short* __restrict__ xb,
            int* __restrict__ cnt, float* __restrict__ g,
            float* __restrict__ gsum, float* __restrict__ gsumsq) {
  int tid = blockIdx.x * 256 + threadIdx.x;
  size_t i = (size_t)tid * 4;
  if (i < (size_t)N_NODES_C * NODE_DIM_C) {
    float4 v = *(const float4*)&x[i];
    uint2 o;
    o.x = (unsigned)f2bf(v.x) | ((unsigned)f2bf(v.y) << 16);
    o.y = (unsigned)f2bf(v.z) | ((unsigned)f2bf(v.w) << 16);
    *(uint2*)&xb[i] = o;
  }
  if (tid < N_NODES_C) cnt[tid] = 0;
  if (tid < N_GRAPHS_C * HID) g[tid] = 0.f;
  if (tid < HID) { gsum[tid] = 0.f; gsumsq[tid] = 0.f; }
}

// ------- weight prep: 6 MLP mats -> wT[m][n*128+k]; node_w -> nwT[n*64+k] ---
__global__ __launch_bounds__(256)
void k_prep_w(const float* __restrict__ w1, const float* __restrict__ w2,
              const float* __restrict__ nodew, unsigned short* __restrict__ wT) {
  int m = blockIdx.x;  // 0..6
  if (m < 6) {
    const float* src = (m < 3) ? (w1 + (size_t)m * HID * HID)
                               : (w2 + (size_t)(m - 3) * HID * HID);
    unsigned short* dst = wT + (size_t)m * HID * HID;
    for (int i = threadIdx.x; i < HID * HID; i += 256) {
      int n = i >> 7, k = i & 127;
      dst[n * HID + k] = f2bf(src[k * HID + n]);
    }
  } else {
    unsigned short* dst = wT + (size_t)6 * HID * HID;  // [128][64]
    for (int i = threadIdx.x; i < HID * NODE_DIM_C; i += 256) {
      int n = i >> 6, k = i & 63;
      dst[n * NODE_DIM_C + k] = f2bf(nodew[k * HID + n]);
    }
  }
}

// ------- node encoder via MFMA: h = bf16(x_bf @ node_w + node_b), K=64 ------
__global__ __launch_bounds__(256)
void k_node_mfma(const unsigned short* __restrict__ xb,
                 const unsigned short* __restrict__ nwT,
                 const float* __restrict__ bias, unsigned short* __restrict__ h) {
  const int LD = NODE_DIM_C + 8;  // 72
  __shared__ unsigned short a_lds[128 * LD];  // 18 KB
  __shared__ unsigned short w_lds[128 * LD];  // 18 KB
  int t = threadIdx.x;
  int row0 = blockIdx.x * 128;
  {
    int r = t >> 3, c = t & 7;
#pragma unroll
    for (int it = 0; it < 4; ++it) {
      int row = it * 32 + r;
      int grow = row0 + row;
      uint4 va = (grow < N_NODES_C)
                     ? ((const uint4*)(xb + (size_t)grow * NODE_DIM_C))[c]
                     : make_uint4(0, 0, 0, 0);
      *(uint4*)&a_lds[row * LD + c * 8] = va;
      uint4 vw = ((const uint4*)(nwT + (size_t)row * NODE_DIM_C))[c];
      *(uint4*)&w_lds[row * LD + c * 8] = vw;
    }
  }
  __syncthreads();

  int lane = t & 63;
  int w = t >> 6;
  int l15 = lane & 15;
  int q = lane >> 4;

  f32x4 acc[2][8];
#pragma unroll
  for (int rt = 0; rt < 2; ++rt)
#pragma unroll
    for (int nt = 0; nt < 8; ++nt) acc[rt][nt] = (f32x4)0.f;

#pragma unroll
  for (int kk = 0; kk < 2; ++kk) {
    int k0 = kk * 32;
    bf16x8 af[2];
#pragma unroll
    for (int rt = 0; rt < 2; ++rt) {
      int arow = w * 32 + rt * 16 + l15;
      af[rt] = *(const bf16x8*)&a_lds[arow * LD + k0 + q * 8];
    }
#pragma unroll
    for (int nt = 0; nt < 8; ++nt) {
      bf16x8 bf = *(const bf16x8*)&w_lds[(nt * 16 + l15) * LD + k0 + q * 8];
#pragma unroll
      for (int rt = 0; rt < 2; ++rt)
        acc[rt][nt] = __builtin_amdgcn_mfma_f32_16x16x32_bf16(af[rt], bf, acc[rt][nt], 0, 0, 0);
    }
  }

#pragma unroll
  for (int nt = 0; nt < 8; ++nt) {
    int gcol = nt * 16 + l15;
    float bv = bias[gcol];
#pragma unroll
    for (int rt = 0; rt < 2; ++rt) {
#pragma unroll
      for (int i = 0; i < 4; ++i) {
        int grow = row0 + w * 32 + rt * 16 + q * 4 + i;
        if (grow < N_NODES_C) h[(size_t)grow * HID + gcol] = f2bf(acc[rt][nt][i] + bv);
      }
    }
  }
}

// ---------------- CSR build (counting sort by dst) ----------------
__global__ __launch_bounds__(256)
void k_histogram(const int* __restrict__ dst, int* __restrict__ counts) {
  int e = blockIdx.x * 256 + threadIdx.x;
  if (e < N_EDGES_C) atomicAdd(&counts[dst[e]], 1);
}

__global__ __launch_bounds__(256)
void k_blocksum(const int* __restrict__ cnt, int* __restrict__ partial) {
  __shared__ int ls[4];
  int t = threadIdx.x;
  int i = blockIdx.x * 256 + t;
  int v = (i < N_NODES_C) ? cnt[i] : 0;
#pragma unroll
  for (int o = 32; o > 0; o >>= 1) v += __shfl_down(v, o, 64);
  if ((t & 63) == 0) ls[t >> 6] = v;
  __syncthreads();
  if (t == 0) partial[blockIdx.x] = ls[0] + ls[1] + ls[2] + ls[3];
}

__global__ __launch_bounds__(256)
void k_scanpartials(const int* __restrict__ partial, int* __restrict__ partial_off) {
  __shared__ int s[256];
  int t = threadIdx.x;
  int v = (t < SCAN_NBLK) ? partial[t] : 0;
  s[t] = v;
  __syncthreads();
  for (int d = 1; d < 256; d <<= 1) {
    int x = (t >= d) ? s[t - d] : 0;
    __syncthreads();
    s[t] += x;
    __syncthreads();
  }
  if (t < SCAN_NBLK) partial_off[t] = s[t] - v;
}

__global__ __launch_bounds__(256)
void k_apply(int* __restrict__ cnt_cursor, const int* __restrict__ partial_off,
             int* __restrict__ row_ptr) {
  __shared__ int s[256];
  int t = threadIdx.x;
  int i = blockIdx.x * 256 + t;
  int v = (i < N_NODES_C) ? cnt_cursor[i] : 0;
  s[t] = v;
  __syncthreads();
  for (int d = 1; d < 256; d <<= 1) {
    int x = (t >= d) ? s[t - d] : 0;
    __syncthreads();
    s[t] += x;
    __syncthreads();
  }
  int excl = s[t] - v + partial_off[blockIdx.x];
  if (i < N_NODES_C) {
    row_ptr[i] = excl;
    cnt_cursor[i] = excl;
  }
  if (i == 0) row_ptr[N_NODES_C] = N_EDGES_C;
}

// bucket: single 8B scattered store per edge
__global__ __launch_bounds__(256)
void k_bucket(const int* __restrict__ dst, const int* __restrict__ srcArr,
              int* __restrict__ cursor, int2* __restrict__ edata) {
  int e = blockIdx.x * 256 + threadIdx.x;
  if (e < N_EDGES_C) {
    int d = dst[e];
    int s = srcArr[e];
    int p = atomicAdd(&cursor[d], 1);
    edata[p] = make_int2(e, s);
  }
}

// ---- edge encoder via MFMA (round-11 proven structure):
// ea8[i] = fp8(eattr[edata[i].x] @ ew + eb); bf16 LDS out-tile stride 132
// (conflict-free epilogue), fp8 convert in coalesced copy-out; src_perm side out.
#define EE_LDW 40   // A/W row stride (shorts)
#define EE_OSW 132  // out tile row stride: epilogue banks (8q+l15/2), free
__global__ __launch_bounds__(256)
void k_edge_encode(const int2* __restrict__ edata, const float* __restrict__ eattr,
                   const float* __restrict__ ew, const float* __restrict__ ebias,
                   unsigned char* __restrict__ ea8, int* __restrict__ src_perm) {
  __shared__ unsigned short smem[128 * EE_OSW];  // 33 KB; overlays A,W then OUT
  unsigned short* a_lds = smem;                  // [128][EE_LDW]
  unsigned short* w_lds = smem + 128 * EE_LDW;   // [128][EE_LDW]
  int t = threadIdx.x;
  int EB = blockIdx.x * 128;

  // stage W: one thread per output column n
  if (t < 128) {
    unsigned short tmp[16];
#pragma unroll
    for (int k = 0; k < 16; ++k) tmp[k] = f2bf(ew[k * HID + t]);
    uint4* wr = (uint4*)&w_lds[t * EE_LDW];
    wr[0] = *(uint4*)&tmp[0];
    wr[1] = *(uint4*)&tmp[8];
    wr[2] = make_uint4(0, 0, 0, 0);
    wr[3] = make_uint4(0, 0, 0, 0);
  }
  // stage A: 2 threads per edge
  {
    int edge = t >> 1, half = t & 1;
    int gi = EB + edge;
    float4 v0 = make_float4(0, 0, 0, 0), v1 = v0;
    if (gi < N_EDGES_C) {
      int2 ed = edata[gi];
      if (half == 0) src_perm[gi] = ed.y;
      const float4* p = (const float4*)(eattr + (size_t)ed.x * EDGE_DIM_C + half * 8);
      v0 = p[0];
      v1 = p[1];
    }
    unsigned short tmp[8] = {f2bf(v0.x), f2bf(v0.y), f2bf(v0.z), f2bf(v0.w),
                             f2bf(v1.x), f2bf(v1.y), f2bf(v1.z), f2bf(v1.w)};
    *(uint4*)&a_lds[edge * EE_LDW + half * 8] = *(uint4*)tmp;
    *(uint4*)&a_lds[edge * EE_LDW + 16 + half * 8] = make_uint4(0, 0, 0, 0);
  }
  __syncthreads();

  int lane = t & 63;
  int w = t >> 6;
  int l15 = lane & 15;
  int q = lane >> 4;

  f32x4 acc[2][8];
  {
    bf16x8 af[2];
#pragma unroll
    for (int rt = 0; rt < 2; ++rt) {
      int arow = w * 32 + rt * 16 + l15;
      af[rt] = *(const bf16x8*)&a_lds[arow * EE_LDW + q * 8];
    }
#pragma unroll
    for (int nt = 0; nt < 8; ++nt) {
      bf16x8 bf = *(const bf16x8*)&w_lds[(nt * 16 + l15) * EE_LDW + q * 8];
#pragma unroll
      for (int rt = 0; rt < 2; ++rt)
        acc[rt][nt] = __builtin_amdgcn_mfma_f32_16x16x32_bf16(
            af[rt], bf, (f32x4)0.f, 0, 0, 0);
    }
  }
  __syncthreads();  // smem becomes the output tile [128][EE_OSW]

#pragma unroll
  for (int nt = 0; nt < 8; ++nt) {
    int col = nt * 16 + l15;
    float bv = ebias[col];
#pragma unroll
    for (int rt = 0; rt < 2; ++rt) {
#pragma unroll
      for (int i = 0; i < 4; ++i) {
        int row = w * 32 + rt * 16 + q * 4 + i;
        smem[row * EE_OSW + col] = f2bf(acc[rt][nt][i] + bv);
      }
    }
  }
  __syncthreads();

  int valid = min(128, N_EDGES_C - EB);
  for (int i = t; i < valid * 32; i += 256) {
    int row = i >> 5, c = i & 31;
    uint2 v = *(const uint2*)&smem[row * EE_OSW + c * 4];
    float2 p0 = bfp2f(v.x);
    float2 p1 = bfp2f(v.y);
    int r = __builtin_amdgcn_cvt_pk_fp8_f32(p0.x, p0.y, 0, false);
    r = __builtin_amdgcn_cvt_pk_fp8_f32(p1.x, p1.y, r, true);
    *(unsigned*)&ea8[((size_t)EB + row) * 128 + c * 4] = (unsigned)r;
  }
}

// -------- aggregate: z[n] = act(in[n]) + sum_e relu(act(in[src_e]) + ea_e) --
// ACT=false: act(v)=v (layer 0, in = h). ACT=true: act(v)=relu(v*sc+sh)
// (layers 1,2: in = t2bf pre-BN; BN+relu fused into the loads).
template <bool ACT>
__global__ __launch_bounds__(256)
void k_aggregate(const unsigned* __restrict__ in32, const unsigned char* __restrict__ ea8,
                 const int* __restrict__ src_p, const int* __restrict__ row_ptr,
                 const float* __restrict__ scb, const float* __restrict__ shb,
                 unsigned short* __restrict__ z) {
  int t = threadIdx.x;
  int lane = t & 63;
  int wave = t >> 6;
  int node = blockIdx.x * 4 + wave;
  if (node >= N_NODES_C) return;
  float sc0 = 1.f, sc1 = 1.f, sh0 = 0.f, sh1 = 0.f;
  if constexpr (ACT) {
    int f0 = lane * 2;
    sc0 = scb[f0]; sc1 = scb[f0 + 1];
    sh0 = shb[f0]; sh1 = shb[f0 + 1];
  }
  auto act = [&](float2 p) -> float2 {
    if constexpr (ACT)
      return make_float2(fmaxf(p.x * sc0 + sh0, 0.f), fmaxf(p.y * sc1 + sh1, 0.f));
    else
      return p;
  };
  float2 base = act(bfp2f(in32[(size_t)node * 64 + lane]));
  float acc0 = base.x, acc1 = base.y;
  int beg = row_ptr[node], end = row_ptr[node + 1];
  const unsigned char* eap = ea8 + lane * 2;
  int j = beg;
  for (; j + 8 <= end; j += 8) {
    int s0 = src_p[j],     s1 = src_p[j + 1], s2 = src_p[j + 2], s3 = src_p[j + 3];
    int s4 = src_p[j + 4], s5 = src_p[j + 5], s6 = src_p[j + 6], s7 = src_p[j + 7];
    unsigned g0 = in32[(size_t)s0 * 64 + lane];
    unsigned g1 = in32[(size_t)s1 * 64 + lane];
    unsigned g2 = in32[(size_t)s2 * 64 + lane];
    unsigned g3 = in32[(size_t)s3 * 64 + lane];
    unsigned g4 = in32[(size_t)s4 * 64 + lane];
    unsigned g5 = in32[(size_t)s5 * 64 + lane];
    unsigned g6 = in32[(size_t)s6 * 64 + lane];
    unsigned g7 = in32[(size_t)s7 * 64 + lane];
    unsigned short u0 = *(const unsigned short*)(eap + (size_t)j * 128);
    unsigned short u1 = *(const unsigned short*)(eap + (size_t)(j + 1) * 128);
    unsigned short u2 = *(const unsigned short*)(eap + (size_t)(j + 2) * 128);
    unsigned short u3 = *(const unsigned short*)(eap + (size_t)(j + 3) * 128);
    unsigned short u4 = *(const unsigned short*)(eap + (size_t)(j + 4) * 128);
    unsigned short u5 = *(const unsigned short*)(eap + (size_t)(j + 5) * 128);
    unsigned short u6 = *(const unsigned short*)(eap + (size_t)(j + 6) * 128);
    unsigned short u7 = *(const unsigned short*)(eap + (size_t)(j + 7) * 128);
    float2 a0 = act(bfp2f(g0)), a1 = act(bfp2f(g1)), a2 = act(bfp2f(g2)), a3 = act(bfp2f(g3));
    float2 a4 = act(bfp2f(g4)), a5 = act(bfp2f(g5)), a6 = act(bfp2f(g6)), a7 = act(bfp2f(g7));
    float2 e0 = fp8p2f(u0), e1 = fp8p2f(u1), e2 = fp8p2f(u2), e3 = fp8p2f(u3);
    float2 e4 = fp8p2f(u4), e5 = fp8p2f(u5), e6 = fp8p2f(u6), e7 = fp8p2f(u7);
    acc0 += fmaxf(a0.x + e0.x, 0.f) + fmaxf(a1.x + e1.x, 0.f) +
            fmaxf(a2.x + e2.x, 0.f) + fmaxf(a3.x + e3.x, 0.f) +
            fmaxf(a4.x + e4.x, 0.f) + fmaxf(a5.x + e5.x, 0.f) +
            fmaxf(a6.x + e6.x, 0.f) + fmaxf(a7.x + e7.x, 0.f);
    acc1 += fmaxf(a0.y + e0.y, 0.f) + fmaxf(a1.y + e1.y, 0.f) +
            fmaxf(a2.y + e2.y, 0.f) + fmaxf(a3.y + e3.y, 0.f) +
            fmaxf(a4.y + e4.y, 0.f) + fmaxf(a5.y + e5.y, 0.f) +
            fmaxf(a6.y + e6.y, 0.f) + fmaxf(a7.y + e7.y, 0.f);
  }
  for (; j + 4 <= end; j += 4) {
    int s0 = src_p[j], s1 = src_p[j + 1], s2 = src_p[j + 2], s3 = src_p[j + 3];
    unsigned g0 = in32[(size_t)s0 * 64 + lane];
    unsigned g1 = in32[(size_t)s1 * 64 + lane];
    unsigned g2 = in32[(size_t)s2 * 64 + lane];
    unsigned g3 = in32[(size_t)s3 * 64 + lane];
    unsigned short u0 = *(const unsigned short*)(eap + (size_t)j * 128);
    unsigned short u1 = *(const unsigned short*)(eap + (size_t)(j + 1) * 128);
    unsigned short u2 = *(const unsigned short*)(eap + (size_t)(j + 2) * 128);
    unsigned short u3 = *(const unsigned short*)(eap + (size_t)(j + 3) * 128);
    float2 a0 = act(bfp2f(g0)), a1 = act(bfp2f(g1)), a2 = act(bfp2f(g2)), a3 = act(bfp2f(g3));
    float2 e0 = fp8p2f(u0), e1 = fp8p2f(u1), e2 = fp8p2f(u2), e3 = fp8p2f(u3);
    acc0 += fmaxf(a0.x + e0.x, 0.f) + fmaxf(a1.x + e1.x, 0.f) +
            fmaxf(a2.x + e2.x, 0.f) + fmaxf(a3.x + e3.x, 0.f);
    acc1 += fmaxf(a0.y + e0.y, 0.f) + fmaxf(a1.y + e1.y, 0.f) +
            fmaxf(a2.y + e2.y, 0.f) + fmaxf(a3.y + e3.y, 0.f);
  }
  for (; j < end; ++j) {
    int s0 = src_p[j];
    float2 a0 = act(bfp2f(in32[(size_t)s0 * 64 + lane]));
    float2 e0 = fp8p2f(*(const unsigned short*)(eap + (size_t)j * 128));
    acc0 += fmaxf(a0.x + e0.x, 0.f);
    acc1 += fmaxf(a0.y + e0.y, 0.f);
  }
  unsigned packed = (unsigned)f2bf(acc0) | ((unsigned)f2bf(acc1) << 16);
  *(unsigned*)&z[(size_t)node * HID + lane * 2] = packed;
}

// ---- fused MLP: t2 = (relu(z@w1+b1))@w2+b2, both GEMMs in one kernel ------
__global__ __launch_bounds__(256)
void k_mlp_fused(const unsigned short* __restrict__ in,
                 const unsigned short* __restrict__ w1T,
                 const float* __restrict__ b1,
                 const unsigned short* __restrict__ w2T,
                 const float* __restrict__ b2,
                 unsigned short* __restrict__ outb,
                 float* __restrict__ gsum, float* __restrict__ gsumsq) {
  const int LDA = HID + 8;  // 136
  const int OS = 132;       // t1 tile stride: epilogue write conflict-free
  __shared__ unsigned short a_lds[128 * LDA];  // 34.8 KB (z, then t1 @ stride OS)
  __shared__ unsigned short w_lds[128 * LDA];  // 34.8 KB (w1T, then w2T)
  int t = threadIdx.x;
  int row0 = blockIdx.x * 128;
  {
    int r = t >> 4, chunk = t & 15;
#pragma unroll
    for (int it = 0; it < 8; ++it) {
      int row = it * 16 + r;
      int grow = row0 + row;
      uint4 va = (grow < N_NODES_C)
                     ? ((const uint4*)(in + (size_t)grow * HID))[chunk]
                     : make_uint4(0, 0, 0, 0);
      *(uint4*)&a_lds[row * LDA + chunk * 8] = va;
      uint4 vw = ((const uint4*)(w1T + (size_t)row * HID))[chunk];
      *(uint4*)&w_lds[row * LDA + chunk * 8] = vw;
    }
  }
  __syncthreads();

  int lane = t & 63;
  int w = t >> 6;
  int l15 = lane & 15;
  int q = lane >> 4;

  // ---- pass 1: z @ w1 ----
  f32x4 acc[2][8];
#pragma unroll
  for (int rt = 0; rt < 2; ++rt)
#pragma unroll
    for (int nt = 0; nt < 8; ++nt) acc[rt][nt] = (f32x4)0.f;

#pragma unroll
  for (int kk = 0; kk < 4; ++kk) {
    int k0 = kk * 32;
    bf16x8 af[2];
#pragma unroll
    for (int rt = 0; rt < 2; ++rt) {
      int arow = w * 32 + rt * 16 + l15;
      af[rt] = *(const bf16x8*)&a_lds[arow * LDA + k0 + q * 8];
    }
#pragma unroll
    for (int nt = 0; nt < 8; ++nt) {
      int brow = nt * 16 + l15;
      bf16x8 bf = *(const bf16x8*)&w_lds[brow * LDA + k0 + q * 8];
#pragma unroll
      for (int rt = 0; rt < 2; ++rt)
        acc[rt][nt] = __builtin_amdgcn_mfma_f32_16x16x32_bf16(af[rt], bf, acc[rt][nt], 0, 0, 0);
    }
  }
  __syncthreads();  // all pass-1 LDS reads done; safe to overwrite

  // t1 = bf16(relu(acc + b1)) -> a_lds at stride OS; restage w2T -> w_lds
#pragma unroll
  for (int nt = 0; nt < 8; ++nt) {
    int col = nt * 16 + l15;
    float bv = b1[col];
#pragma unroll
    for (int rt = 0; rt < 2; ++rt) {
#pragma unroll
      for (int i = 0; i < 4; ++i) {
        int row = w * 32 + rt * 16 + q * 4 + i;
        a_lds[row * OS + col] = f2bf(fmaxf(acc[rt][nt][i] + bv, 0.f));
      }
    }
  }
  {
    int r = t >> 4, chunk = t & 15;
#pragma unroll
    for (int it = 0; it < 8; ++it) {
      int row = it * 16 + r;
      uint4 vw = ((const uint4*)(w2T + (size_t)row * HID))[chunk];
      *(uint4*)&w_lds[row * LDA + chunk * 8] = vw;
    }
  }
  __syncthreads();

  // ---- pass 2: t1 @ w2 ----
#pragma unroll
  for (int rt = 0; rt < 2; ++rt)
#pragma unroll
    for (int nt = 0; nt < 8; ++nt) acc[rt][nt] = (f32x4)0.f;

#pragma unroll
  for (int kk = 0; kk < 4; ++kk) {
    int k0 = kk * 32;
    bf16x8 af[2];
#pragma unroll
    for (int rt = 0; rt < 2; ++rt) {
      int arow = w * 32 + rt * 16 + l15;
      af[rt] = *(const bf16x8*)&a_lds[arow * OS + k0 + q * 8];
    }
#pragma unroll
    for (int nt = 0; nt < 8; ++nt) {
      int brow = nt * 16 + l15;
      bf16x8 bf = *(const bf16x8*)&w_lds[brow * LDA + k0 + q * 8];
#pragma unroll
      for (int rt = 0; rt < 2; ++rt)
        acc[rt][nt] = __builtin_amdgcn_mfma_f32_16x16x32_bf16(af[rt], bf, acc[rt][nt], 0, 0, 0);
    }
  }

  float sp[8], qp[8];
#pragma unroll
  for (int nt = 0; nt < 8; ++nt) { sp[nt] = 0.f; qp[nt] = 0.f; }

#pragma unroll
  for (int nt = 0; nt < 8; ++nt) {
    int gcol = nt * 16 + l15;
    float bv = b2[gcol];
#pragma unroll
    for (int rt = 0; rt < 2; ++rt) {
#pragma unroll
      for (int i = 0; i < 4; ++i) {
        int grow = row0 + w * 32 + rt * 16 + q * 4 + i;
        bool ok = (grow < N_NODES_C);
        float v = acc[rt][nt][i] + bv;
        if (ok) outb[(size_t)grow * HID + gcol] = f2bf(v);
        float c = ok ? v : 0.f;
        sp[nt] += c;
        qp[nt] += c * c;
      }
    }
  }

  __syncthreads();  // all pass-2 LDS reads done; reuse a_lds as reduce scratch
  float* sred = (float*)a_lds;        // [128][16]
  float* qred = sred + 128 * 16;
  int slot = w * 4 + q;
#pragma unroll
  for (int nt = 0; nt < 8; ++nt) {
    int gcol = nt * 16 + l15;
    sred[gcol * 16 + slot] = sp[nt];
    qred[gcol * 16 + slot] = qp[nt];
  }
  __syncthreads();
  if (t < 128) {
    float s = 0.f;
#pragma unroll
    for (int i = 0; i < 16; ++i) s += sred[t * 16 + i];
    atomicAdd(&gsum[t], s);
  } else {
    int f = t - 128;
    float s = 0.f;
#pragma unroll
    for (int i = 0; i < 16; ++i) s += qred[f * 16 + i];
    atomicAdd(&gsumsq[f], s);
  }
}

// finalize BN for the NEXT aggregate: sc/sh from stats; re-zero stats buffers
__global__ void k_bn_finalize(float* __restrict__ gsum, float* __restrict__ gsumsq,
                              const float* __restrict__ gamma, const float* __restrict__ beta,
                              float* __restrict__ scb, float* __restrict__ shb) {
  int f = threadIdx.x;  // 128
  float mean = gsum[f] * (1.f / N_NODES_C);
  float var = gsumsq[f] * (1.f / N_NODES_C) - mean * mean;
  float inv = rsqrtf(var + BN_EPS_C);
  float sc = gamma[f] * inv;
  scb[f] = sc;
  shb[f] = beta[f] - mean * sc;
  gsum[f] = 0.f;
  gsumsq[f] = 0.f;
}

// BN (from stats) + relu + global_add_pool fused (last layer)
__global__ __launch_bounds__(128)
void k_bn_relu_pool(const unsigned short* __restrict__ t2, const float* __restrict__ gsum,
                    const float* __restrict__ gsumsq, const float* __restrict__ gamma,
                    const float* __restrict__ beta, const int* __restrict__ batch,
                    float* __restrict__ g) {
  int t = threadIdx.x;
  float mean = gsum[t] * (1.f / N_NODES_C);
  float var = gsumsq[t] * (1.f / N_NODES_C) - mean * mean;
  float inv = rsqrtf(var + BN_EPS_C);
  float sc = gamma[t] * inv;
  float sh = beta[t] - mean * sc;
  int n0 = blockIdx.x * 64;
  if (n0 >= N_NODES_C) return;
  int end = min(n0 + 64, N_NODES_C);
  int cur = batch[n0];
  float acc = 0.f;
  for (int n = n0; n < end; ++n) {
    int b = batch[n];
    if (b != cur) {
      atomicAdd(&g[cur * HID + t], acc);
      acc = 0.f;
      cur = b;
    }
    acc += fmaxf(bf2f(t2[(size_t)n * HID + t]) * sc + sh, 0.f);
  }
  atomicAdd(&g[cur * HID + t], acc);
}

// ---------------- head: relu(g@w1+b1)@w2+b2 ----------------
__global__ __launch_bounds__(128)
void k_head(const float* __restrict__ g, const float* __restrict__ w1,
            const float* __restrict__ b1, const float* __restrict__ w2,
            const float* __restrict__ b2, float* __restrict__ out) {
  __shared__ float gs[HID];
  __shared__ float red[HID * 2];
  int gi = blockIdx.x, t = threadIdx.x;
  gs[t] = g[gi * HID + t];
  __syncthreads();
  float acc = b1[t];
#pragma unroll 8
  for (int k = 0; k < HID; ++k) acc += gs[k] * w1[k * HID + t];
  float hid = fmaxf(acc, 0.f);
  red[t * 2] = hid * w2[t * 2];
  red[t * 2 + 1] = hid * w2[t * 2 + 1];
  __syncthreads();
  for (int s = 64; s > 0; s >>= 1) {
    if (t < s) { red[t * 2] += red[(t + s) * 2]; red[t * 2 + 1] += red[(t + s) * 2 + 1]; }
    __syncthreads();
  }
  if (t == 0) {
    out[gi * 2] = red[0] + b2[0];
    out[gi * 2 + 1] = red[1] + b2[1];
  }
}

extern "C" void kernel_launch(void* const* d_in, const int* in_sizes, int n_in,
                              void* d_out, int out_size, void* d_ws, size_t ws_size,
                              hipStream_t stream) {
  const float* x      = (const float*)d_in[0];
  const int*   eidx   = (const int*)d_in[1];
  const float* eattr  = (const float*)d_in[2];
  const int*   batch  = (const int*)d_in[3];
  const float* node_w = (const float*)d_in[4];
  const float* node_b = (const float*)d_in[5];
  const float* edge_w = (const float*)d_in[6];
  const float* edge_b = (const float*)d_in[7];
  const float* mlp_w1 = (const float*)d_in[8];
  const float* mlp_b1 = (const float*)d_in[9];
  const float* mlp_w2 = (const float*)d_in[10];
  const float* mlp_b2 = (const float*)d_in[11];
  const float* bn_g   = (const float*)d_in[12];
  const float* bn_b   = (const float*)d_in[13];
  const float* hw1    = (const float*)d_in[14];
  const float* hb1    = (const float*)d_in[15];
  const float* hw2    = (const float*)d_in[16];
  const float* hb2    = (const float*)d_in[17];
  const int* srcArr = eidx;
  const int* dstArr = eidx + N_EDGES_C;

  char* wsp = (char*)d_ws;
  size_t off = 0;
  auto alloc = [&](size_t bytes) {
    void* p = wsp + off;
    off += (bytes + 255) & ~(size_t)255;
    return p;
  };
  unsigned short* h    = (unsigned short*)alloc((size_t)N_NODES_C * HID * 2);   // 12.8 MB
  unsigned short* zbf  = (unsigned short*)alloc((size_t)N_NODES_C * HID * 2);   // 12.8 MB
  unsigned short* t2bf = (unsigned short*)alloc((size_t)N_NODES_C * HID * 2);   // 12.8 MB
  unsigned char* ea8   = (unsigned char*)alloc((size_t)N_EDGES_C * HID);        // 76.8 MB
  unsigned short* xb   = (unsigned short*)alloc((size_t)N_NODES_C * NODE_DIM_C * 2);  // 6.4 MB
  unsigned short* wT   = (unsigned short*)alloc(((size_t)6 * HID * HID + HID * NODE_DIM_C) * 2);
  int* row_ptr   = (int*)alloc((N_NODES_C + 1) * 4);
  int* cnt_cur   = (int*)alloc(N_NODES_C * 4);
  int2* edata    = (int2*)alloc((size_t)N_EDGES_C * 8);  // 4.8 MB
  int* src_perm  = (int*)alloc((size_t)N_EDGES_C * 4);
  int* partial   = (int*)alloc(256 * 4);
  int* partial_off = (int*)alloc(256 * 4);
  float* gsum    = (float*)alloc(HID * 4);
  float* gsumsq  = (float*)alloc(HID * 4);
  float* scb     = (float*)alloc(HID * 4);
  float* shb     = (float*)alloc(HID * 4);
  float* g       = (float*)alloc((size_t)N_GRAPHS_C * HID * 4);
  unsigned short* nwT = wT + (size_t)6 * HID * HID;

  k_x2bf<<<(N_NODES_C * NODE_DIM_C / 4 + 255) / 256, 256, 0, stream>>>(
      x, xb, cnt_cur, g, gsum, gsumsq);
  k_prep_w<<<7, 256, 0, stream>>>(mlp_w1, mlp_w2, node_w, wT);
  k_node_mfma<<<(N_NODES_C + 127) / 128, 256, 0, stream>>>(xb, nwT, node_b, h);
  k_histogram<<<(N_EDGES_C + 255) / 256, 256, 0, stream>>>(dstArr, cnt_cur);
  k_blocksum<<<SCAN_NBLK, 256, 0, stream>>>(cnt_cur, partial);
  k_scanpartials<<<1, 256, 0, stream>>>(partial, partial_off);
  k_apply<<<SCAN_NBLK, 256, 0, stream>>>(cnt_cur, partial_off, row_ptr);
  k_bucket<<<(N_EDGES_C + 255) / 256, 256, 0, stream>>>(dstArr, srcArr, cnt_cur,
                                                        edata);
  k_edge_encode<<<(N_EDGES_C + 127) / 128, 256, 0, stream>>>(edata, eattr, edge_w,
                                                             edge_b, ea8, src_perm);

  const int GB = (N_NODES_C + 127) / 128;  // 391
  const int AB = (N_NODES_C + 3) / 4;
  for (int l = 0; l < 3; ++l) {
    if (l == 0) {
      k_aggregate<false><<<AB, 256, 0, stream>>>((const unsigned*)h, ea8, src_perm,
                                                 row_ptr, nullptr, nullptr, zbf);
    } else {
      k_aggregate<true><<<AB, 256, 0, stream>>>((const unsigned*)t2bf, ea8, src_perm,
                                                row_ptr, scb, shb, zbf);
    }
    k_mlp_fused<<<GB, 256, 0, stream>>>(
        zbf, wT + (size_t)l * HID * HID, mlp_b1 + l * HID,
        wT + (size_t)(3 + l) * HID * HID, mlp_b2 + l * HID, t2bf, gsum, gsumsq);
    if (l < 2) {
      k_bn_finalize<<<1, HID, 0, stream>>>(gsum, gsumsq, bn_g + l * HID,
                                           bn_b + l * HID, scb, shb);
    } else {
      k_bn_relu_pool<<<(N_NODES_C + 63) / 64, 128, 0, stream>>>(
          t2bf, gsum, gsumsq, bn_g + l * HID, bn_b + l * HID, batch, g);
    }
  }
  k_head<<<N_GRAPHS_C, 128, 0, stream>>>(g, hw1, hb1, hw2, hb2, (float*)d_out);
}